// Round 11
// baseline (63.520 us; speedup 1.0000x reference)
//
#include <hip/hip_runtime.h>

typedef __attribute__((ext_vector_type(8))) short short8;
typedef __attribute__((ext_vector_type(4))) float f32x4;

#define D128 128

// fp32 -> bf16 round-to-nearest-even (bit pattern)
__device__ __forceinline__ unsigned short f2bf(float f) {
    unsigned int u = __float_as_uint(f);
    u += 0x7fffu + ((u >> 16) & 1u);
    return (unsigned short)(u >> 16);
}

// ---------------------------------------------------------------------------
// Pre-kernel: W (fp32 [k=128][col=128]) -> bf16 fragments in ws.
// fragment f = of*4+kk; lane l holds 8 bf16 at ws[(f*64+l)*8] =
// W[k = kk*32 + (l>>4)*8 + j][col = of*16 + (l&15)]
// Used as the MFMA *A*-operand (swapped-operand trick).
// ---------------------------------------------------------------------------
__global__ __launch_bounds__(64)
void convert_w_kernel(const float* __restrict__ w, unsigned short* __restrict__ wsb) {
    int t = blockIdx.x * 64 + threadIdx.x;   // 0..2047
    int f = t >> 6;
    int l = t & 63;
    int of = f >> 2, kk = f & 3;
    int col   = of * 16 + (l & 15);
    int kbase = kk * 32 + (l >> 4) * 8;
    short8 v;
    #pragma unroll
    for (int j = 0; j < 8; ++j)
        v[j] = (short)f2bf(w[(kbase + j) * D128 + col]);
    *(short8*)(wsb + (size_t)t * 8) = v;
}

// ---------------------------------------------------------------------------
// Main kernel, swapped-operand MFMA: D = W^T · x^T  (R9 structure).
//   mfma(A = W-frag, B = x-frag) -> D[out][xrow]: xrow = lane&15,
//   out = (lane>>4)*4 + reg (+16*of per fragment).
// Each lane holds 32 output features of ONE x-row -> LN reduce = in-lane
// sums + 2 shfl_xor. Zero LDS, short epilogue chain.
// ONE change vs R9: stores are plain cached (not NT) so the 64B-granule
// per-lane stores merge into full 128B L2 lines -> WRITE_SIZE back to the
// exact 131 MB (R9's NT partial-line stores inflated it to 178 MB while
// actually sustaining 2.9 TB/s of write throughput).
// ---------------------------------------------------------------------------
__global__ __launch_bounds__(128)
void fused_linear_ln_kernel(const float* __restrict__ x,
                            const unsigned short* __restrict__ wsb,
                            const float* __restrict__ bias,
                            float* __restrict__ out)
{
    const int tid  = threadIdx.x;
    const int lane = tid & 63;
    const int wave = tid >> 6;
    const int row  = lane & 15;    // x-row within the wave's 16-row tile
    const int g    = lane >> 4;    // 0..3: k-subgroup on load, out-subgroup on store

    const long row_base = (long)blockIdx.x * 32 + wave * 16;

    // ---- load this wave's 16 rows of x (fp32), cvt to bf16 B-fragments ----
    short8 xfrag[4];
    {
        const float* rp = x + (row_base + row) * D128 + g * 8;
        #pragma unroll
        for (int kk = 0; kk < 4; ++kk) {
            const float4* p = (const float4*)(rp + kk * 32);
            float4 v0 = p[0];
            float4 v1 = p[1];
            short8 a;
            a[0] = (short)f2bf(v0.x); a[1] = (short)f2bf(v0.y);
            a[2] = (short)f2bf(v0.z); a[3] = (short)f2bf(v0.w);
            a[4] = (short)f2bf(v1.x); a[5] = (short)f2bf(v1.y);
            a[6] = (short)f2bf(v1.z); a[7] = (short)f2bf(v1.w);
            xfrag[kk] = a;
        }
    }

    // ---- MFMA: acc[of] holds outs [of*16 + g*4 + r] of x-row `row` ----
    f32x4 acc[8];
    #pragma unroll
    for (int of = 0; of < 8; ++of) acc[of] = (f32x4){0.f, 0.f, 0.f, 0.f};

    #pragma unroll
    for (int kk = 0; kk < 4; ++kk) {
        short8 wfrag[8];
        #pragma unroll
        for (int of = 0; of < 8; ++of)
            wfrag[of] = *(const short8*)(wsb + (size_t)((of * 4 + kk) * 64 + lane) * 8);
        #pragma unroll
        for (int of = 0; of < 8; ++of)
            acc[of] = __builtin_amdgcn_mfma_f32_16x16x32_bf16(
                wfrag[of], xfrag[kk], acc[of], 0, 0, 0);
    }

    // ---- epilogue: + bias, in-lane partials, 2-shuffle row reduce,
    //      normalize, direct cached dwordx4 stores ----
    float s = 0.f, q = 0.f;
    #pragma unroll
    for (int of = 0; of < 8; ++of) {
        f32x4 b4 = *(const f32x4*)(bias + of * 16 + g * 4);
        acc[of] += b4;
        #pragma unroll
        for (int r = 0; r < 4; ++r) {
            float z = acc[of][r];
            s += z;
            q += z * z;
        }
    }
    s += __shfl_xor(s, 16, 64);
    s += __shfl_xor(s, 32, 64);
    q += __shfl_xor(q, 16, 64);
    q += __shfl_xor(q, 32, 64);

    float mean = s * (1.0f / 128.0f);
    float var  = q * (1.0f / 128.0f) - mean * mean;
    float rs   = rsqrtf(var + 1e-5f);

    float* op = out + (row_base + row) * D128 + g * 4;
    #pragma unroll
    for (int of = 0; of < 8; ++of) {
        f32x4 v;
        #pragma unroll
        for (int r = 0; r < 4; ++r) v[r] = (acc[of][r] - mean) * rs;
        *(f32x4*)(op + of * 16) = v;
    }
}

extern "C" void kernel_launch(void* const* d_in, const int* in_sizes, int n_in,
                              void* d_out, int out_size, void* d_ws, size_t ws_size,
                              hipStream_t stream) {
    const float* x    = (const float*)d_in[0];
    const float* w    = (const float*)d_in[1];
    const float* bias = (const float*)d_in[2];
    float* out        = (float*)d_out;

    int nrows = in_sizes[0] / D128;    // 262144
    int grid  = nrows / 32;            // 8192 blocks x 32 rows (2 waves x 16)

    unsigned short* wsb = (unsigned short*)d_ws;
    hipLaunchKernelGGL(convert_w_kernel, dim3(32), dim3(64), 0, stream, w, wsb);
    hipLaunchKernelGGL(fused_linear_ln_kernel, dim3(grid), dim3(128), 0, stream,
                       x, wsb, bias, out);
}

// Round 12
// 56.395 us; speedup vs baseline: 1.1263x; 1.1263x over previous
//
#include <hip/hip_runtime.h>

typedef __attribute__((ext_vector_type(8))) short short8;
typedef __attribute__((ext_vector_type(4))) float f32x4;

#define D128 128
#define TSTRIDE 136   // f32 row stride for 4-row store buffer: 544B, 16B-aligned,
                      // 136%32==8 -> lk groups land 8 banks apart -> exact 2-way (free)

// fp32 -> bf16 round-to-nearest-even (bit pattern)
__device__ __forceinline__ unsigned short f2bf(float f) {
    unsigned int u = __float_as_uint(f);
    u += 0x7fffu + ((u >> 16) & 1u);
    return (unsigned short)(u >> 16);
}

// ---------------------------------------------------------------------------
// Pre-kernel, parallelized: 256 blocks x 64 threads, ONE element each
// (prev: 32 blocks = 32 waves total -> latency-serialized ~4us before main).
// Element t: fragment f = t>>9, lane l = (t>>3)&63, elem j = t&7.
// wsb[(f*64+l)*8 + j] = bf16( w[(kk*32 + (l>>4)*8 + j)*128 + of*16 + (l&15)] )
// with of = f>>2, kk = f&3. Wave stores are 128B contiguous.
// ---------------------------------------------------------------------------
__global__ __launch_bounds__(64)
void convert_w_kernel(const float* __restrict__ w, unsigned short* __restrict__ wsb) {
    int t  = blockIdx.x * 64 + threadIdx.x;  // 0..16383
    int f  = t >> 9;
    int l  = (t >> 3) & 63;
    int j  = t & 7;
    int of = f >> 2, kk = f & 3;
    int col = of * 16 + (l & 15);
    int k   = kk * 32 + (l >> 4) * 8 + j;
    wsb[t] = f2bf(w[k * D128 + col]);
}

// ---------------------------------------------------------------------------
// Main kernel — R8 exactly (best wall: 56.0us). 16 rows/wave, block = 2
// waves. Per-r tiny LDS staging -> coalesced full-line 1KB NT wave-stores.
// ---------------------------------------------------------------------------
__global__ __launch_bounds__(128)
void fused_linear_ln_kernel(const float* __restrict__ x,
                            const unsigned short* __restrict__ wsb,
                            const float* __restrict__ bias,
                            float* __restrict__ out)
{
    __shared__ float tlb[2][4][TSTRIDE];   // 4352 B

    const int tid  = threadIdx.x;
    const int lane = tid & 63;
    const int wave = tid >> 6;
    const int lrow = lane & 15;
    const int lk   = lane >> 4;

    const long row_base = (long)blockIdx.x * 32 + wave * 16;

    // ---- load this wave's 16 rows of x (fp32), cvt to bf16 A fragments ----
    short8 afrag[4];
    {
        const float* rp = x + (row_base + lrow) * D128 + lk * 8;
        #pragma unroll
        for (int kk = 0; kk < 4; ++kk) {
            const float4* p = (const float4*)(rp + kk * 32);
            float4 v0 = p[0];
            float4 v1 = p[1];
            short8 a;
            a[0] = (short)f2bf(v0.x); a[1] = (short)f2bf(v0.y);
            a[2] = (short)f2bf(v0.z); a[3] = (short)f2bf(v0.w);
            a[4] = (short)f2bf(v1.x); a[5] = (short)f2bf(v1.y);
            a[6] = (short)f2bf(v1.z); a[7] = (short)f2bf(v1.w);
            afrag[kk] = a;
        }
    }

    float bias_v[8];
    #pragma unroll
    for (int cf = 0; cf < 8; ++cf) bias_v[cf] = bias[cf * 16 + lrow];

    // ---- MFMA: 4 k-steps x 8 col-fragments ----
    f32x4 acc[8];
    #pragma unroll
    for (int cf = 0; cf < 8; ++cf) acc[cf] = (f32x4){0.f, 0.f, 0.f, 0.f};

    #pragma unroll
    for (int kk = 0; kk < 4; ++kk) {
        short8 bfrag[8];
        #pragma unroll
        for (int cf = 0; cf < 8; ++cf)
            bfrag[cf] = *(const short8*)(wsb + (size_t)((cf * 4 + kk) * 64 + lane) * 8);
        #pragma unroll
        for (int cf = 0; cf < 8; ++cf)
            acc[cf] = __builtin_amdgcn_mfma_f32_16x16x32_bf16(
                afrag[kk], bfrag[cf], acc[cf], 0, 0, 0);
    }

    // ---- epilogue: per r, finish 4 rows (one per lk group), stage in tiny
    //      LDS buffer, store immediately as 2 coalesced NT wave-stores ----
    const int rsel = lane >> 5;          // 0/1
    const int c4   = (lane & 31) * 4;    // col start for read-back/store

    #pragma unroll
    for (int r = 0; r < 4; ++r) {
        float s = 0.f, q = 0.f;
        float zv[8];
        #pragma unroll
        for (int cf = 0; cf < 8; ++cf) {
            float z = acc[cf][r] + bias_v[cf];
            zv[cf] = z;
            s += z;
            q += z * z;
        }
        #pragma unroll
        for (int m = 1; m <= 8; m <<= 1) {
            s += __shfl_xor(s, m, 64);
            q += __shfl_xor(q, m, 64);
        }
        float mean = s * (1.0f / 128.0f);
        float var  = q * (1.0f / 128.0f) - mean * mean;
        float rs   = rsqrtf(var + 1e-5f);

        // lk group holds output row (row_base + lk*4 + r): scatter into buffer row lk
        #pragma unroll
        for (int cf = 0; cf < 8; ++cf)
            tlb[wave][lk][cf * 16 + lrow] = (zv[cf] - mean) * rs;

        // store buffer rows 0..3 -> output rows row_base + 4*j + r
        #pragma unroll
        for (int i2 = 0; i2 < 2; ++i2) {
            int j = i2 * 2 + rsel;
            f32x4 v = *(const f32x4*)&tlb[wave][j][c4];
            __builtin_nontemporal_store(
                v, (f32x4*)(out + (row_base + 4 * j + r) * D128 + c4));
        }
    }
}

extern "C" void kernel_launch(void* const* d_in, const int* in_sizes, int n_in,
                              void* d_out, int out_size, void* d_ws, size_t ws_size,
                              hipStream_t stream) {
    const float* x    = (const float*)d_in[0];
    const float* w    = (const float*)d_in[1];
    const float* bias = (const float*)d_in[2];
    float* out        = (float*)d_out;

    int nrows = in_sizes[0] / D128;    // 262144
    int grid  = nrows / 32;            // 8192 blocks x 32 rows (2 waves x 16)

    unsigned short* wsb = (unsigned short*)d_ws;
    hipLaunchKernelGGL(convert_w_kernel, dim3(256), dim3(64), 0, stream, w, wsb);
    hipLaunchKernelGGL(fused_linear_ln_kernel, dim3(grid), dim3(128), 0, stream,
                       x, wsb, bias, out);
}

// Round 13
// 53.837 us; speedup vs baseline: 1.1799x; 1.0475x over previous
//
#include <hip/hip_runtime.h>

typedef __attribute__((ext_vector_type(8))) short short8;
typedef __attribute__((ext_vector_type(4))) float f32x4;

#define D128 128
#define TSTRIDE 136   // f32 row stride for 4-row store buffer: 544B, 16B-aligned,
                      // 136%32==8 -> lk groups land 8 banks apart -> exact 2-way (free)

// fp32 -> bf16 round-to-nearest-even (bit pattern)
__device__ __forceinline__ unsigned short f2bf(float f) {
    unsigned int u = __float_as_uint(f);
    u += 0x7fffu + ((u >> 16) & 1u);
    return (unsigned short)(u >> 16);
}

// ---------------------------------------------------------------------------
// Pre-kernel (parallel, 256 blocks x 64 threads, one element each):
// W (fp32 [k=128][col=128]) -> bf16 B-fragments in ws.
// wsb[(f*64+l)*8 + j] = bf16( w[(kk*32+(l>>4)*8+j)*128 + cf*16 + (l&15)] ),
// f = cf*4+kk.
// ---------------------------------------------------------------------------
__global__ __launch_bounds__(64)
void convert_w_kernel(const float* __restrict__ w, unsigned short* __restrict__ wsb) {
    int t  = blockIdx.x * 64 + threadIdx.x;  // 0..16383
    int f  = t >> 9;
    int l  = (t >> 3) & 63;
    int j  = t & 7;
    int cf = f >> 2, kk = f & 3;
    int col = cf * 16 + (l & 15);
    int k   = kk * 32 + (l >> 4) * 8 + j;
    wsb[t] = f2bf(w[k * D128 + col]);
}

// ---------------------------------------------------------------------------
// Main kernel — R8 epilogue structure (best wall), now grid-stride 4 tiles
// per block so each wave's NT stores (fire-and-forget) overlap the NEXT
// iteration's independent x-loads + MFMA. Goal: raise per-CU outstanding-
// write duty cycle toward copy-kernel levels (stores currently bunch in the
// last ~20% of each wave's life).
// 16 rows/wave, block = 2 waves = 32 rows/tile.
// ---------------------------------------------------------------------------
__global__ __launch_bounds__(128)
void fused_linear_ln_kernel(const float* __restrict__ x,
                            const unsigned short* __restrict__ wsb,
                            const float* __restrict__ bias,
                            float* __restrict__ out,
                            int ntiles)
{
    __shared__ float tlb[2][4][TSTRIDE];   // 4352 B

    const int tid  = threadIdx.x;
    const int lane = tid & 63;
    const int wave = tid >> 6;
    const int lrow = lane & 15;
    const int lk   = lane >> 4;
    const int gstride = gridDim.x;

    float bias_v[8];
    #pragma unroll
    for (int cf = 0; cf < 8; ++cf) bias_v[cf] = bias[cf * 16 + lrow];

    const int rsel = lane >> 5;          // 0/1
    const int c4   = (lane & 31) * 4;    // col start for read-back/store

    // raw x buffer for the software pipeline: 8 float4
    float4 raw[4][2];

    // ---- prologue: issue loads for first tile ----
    {
        long rb = (long)blockIdx.x * 32 + wave * 16;
        const float* rp = x + (rb + lrow) * D128 + lk * 8;
        #pragma unroll
        for (int kk = 0; kk < 4; ++kk) {
            const float4* p = (const float4*)(rp + kk * 32);
            raw[kk][0] = p[0];
            raw[kk][1] = p[1];
        }
    }

    for (int t = blockIdx.x; t < ntiles; t += gstride) {
        const long row_base = (long)t * 32 + wave * 16;

        // ---- cvt raw -> bf16 A fragments ----
        short8 afrag[4];
        #pragma unroll
        for (int kk = 0; kk < 4; ++kk) {
            float4 v0 = raw[kk][0];
            float4 v1 = raw[kk][1];
            short8 a;
            a[0] = (short)f2bf(v0.x); a[1] = (short)f2bf(v0.y);
            a[2] = (short)f2bf(v0.z); a[3] = (short)f2bf(v0.w);
            a[4] = (short)f2bf(v1.x); a[5] = (short)f2bf(v1.y);
            a[6] = (short)f2bf(v1.z); a[7] = (short)f2bf(v1.w);
            afrag[kk] = a;
        }

        // ---- issue next tile's loads (overlap with MFMA + epilogue + stores) ----
        int tn = t + gstride;
        if (tn < ntiles) {
            long rb = (long)tn * 32 + wave * 16;
            const float* rp = x + (rb + lrow) * D128 + lk * 8;
            #pragma unroll
            for (int kk = 0; kk < 4; ++kk) {
                const float4* p = (const float4*)(rp + kk * 32);
                raw[kk][0] = p[0];
                raw[kk][1] = p[1];
            }
        }

        // ---- MFMA: 4 k-steps x 8 col-fragments ----
        f32x4 acc[8];
        #pragma unroll
        for (int cf = 0; cf < 8; ++cf) acc[cf] = (f32x4){0.f, 0.f, 0.f, 0.f};

        #pragma unroll
        for (int kk = 0; kk < 4; ++kk) {
            short8 bfrag[8];
            #pragma unroll
            for (int cf = 0; cf < 8; ++cf)
                bfrag[cf] = *(const short8*)(wsb + (size_t)((cf * 4 + kk) * 64 + lane) * 8);
            #pragma unroll
            for (int cf = 0; cf < 8; ++cf)
                acc[cf] = __builtin_amdgcn_mfma_f32_16x16x32_bf16(
                    afrag[kk], bfrag[cf], acc[cf], 0, 0, 0);
        }

        // ---- epilogue: per r, finish 4 rows, stage in tiny LDS buffer,
        //      store as 2 coalesced full-line NT wave-stores ----
        #pragma unroll
        for (int r = 0; r < 4; ++r) {
            float s = 0.f, q = 0.f;
            float zv[8];
            #pragma unroll
            for (int cf = 0; cf < 8; ++cf) {
                float z = acc[cf][r] + bias_v[cf];
                zv[cf] = z;
                s += z;
                q += z * z;
            }
            #pragma unroll
            for (int m = 1; m <= 8; m <<= 1) {
                s += __shfl_xor(s, m, 64);
                q += __shfl_xor(q, m, 64);
            }
            float mean = s * (1.0f / 128.0f);
            float var  = q * (1.0f / 128.0f) - mean * mean;
            float rs   = rsqrtf(var + 1e-5f);

            #pragma unroll
            for (int cf = 0; cf < 8; ++cf)
                tlb[wave][lk][cf * 16 + lrow] = (zv[cf] - mean) * rs;

            #pragma unroll
            for (int i2 = 0; i2 < 2; ++i2) {
                int j = i2 * 2 + rsel;
                f32x4 v = *(const f32x4*)&tlb[wave][j][c4];
                __builtin_nontemporal_store(
                    v, (f32x4*)(out + (row_base + 4 * j + r) * D128 + c4));
            }
        }
    }
}

extern "C" void kernel_launch(void* const* d_in, const int* in_sizes, int n_in,
                              void* d_out, int out_size, void* d_ws, size_t ws_size,
                              hipStream_t stream) {
    const float* x    = (const float*)d_in[0];
    const float* w    = (const float*)d_in[1];
    const float* bias = (const float*)d_in[2];
    float* out        = (float*)d_out;

    int nrows  = in_sizes[0] / D128;   // 262144
    int ntiles = nrows / 32;           // 8192
    int grid   = ntiles / 4;           // 2048 blocks x 4 tiles each

    unsigned short* wsb = (unsigned short*)d_ws;
    hipLaunchKernelGGL(convert_w_kernel, dim3(256), dim3(64), 0, stream, w, wsb);
    hipLaunchKernelGGL(fused_linear_ln_kernel, dim3(grid), dim3(128), 0, stream,
                       x, wsb, bias, out, ntiles);
}

// Round 14
// 49.909 us; speedup vs baseline: 1.2727x; 1.0787x over previous
//
#include <hip/hip_runtime.h>

typedef __attribute__((ext_vector_type(8))) short short8;
typedef __attribute__((ext_vector_type(4))) float f32x4;

#define D128 128
#define TSTRIDE 132   // f32 row stride: 132%32==4 -> b128 readback is conflict-free (R6-verified)

// fp32 -> bf16 round-to-nearest-even (bit pattern)
__device__ __forceinline__ unsigned short f2bf(float f) {
    unsigned int u = __float_as_uint(f);
    u += 0x7fffu + ((u >> 16) & 1u);
    return (unsigned short)(u >> 16);
}

// ---------------------------------------------------------------------------
// Pre-kernel (parallel): W (fp32 [k=128][col=128]) -> bf16 fragments in ws.
// wsb[(f*64+l)*8 + j] = bf16( w[(kk*32+(l>>4)*8+j)*128 + of*16 + (l&15)] ),
// f = of*4+kk. Used as the MFMA A-operand (swapped-operand layout).
// ---------------------------------------------------------------------------
__global__ __launch_bounds__(64)
void convert_w_kernel(const float* __restrict__ w, unsigned short* __restrict__ wsb) {
    int t  = blockIdx.x * 64 + threadIdx.x;  // 0..16383
    int f  = t >> 9;
    int l  = (t >> 3) & 63;
    int j  = t & 7;
    int of = f >> 2, kk = f & 3;
    int col = of * 16 + (l & 15);
    int k   = kk * 32 + (l >> 4) * 8 + j;
    wsb[t] = f2bf(w[k * D128 + col]);
}

// ---------------------------------------------------------------------------
// Main kernel — persistent grid (1024 blocks x 8 tiles, all co-resident),
// swapped-operand MFMA (D = W^T x^T: lane owns 32 output features of ONE
// row -> LN reduce = 4 shfl_xor total), per-wave LDS reshape, 8 full-line
// 1KB NT wave-stores per tile. Next-tile x-loads prefetched under MFMA.
// Goal: near-continuous per-CU store stream (fillBuffer shows 7 TB/s is
// available to pure store streams; we were at 2.7).
// ---------------------------------------------------------------------------
__global__ __launch_bounds__(128)
void fused_linear_ln_kernel(const float* __restrict__ x,
                            const unsigned short* __restrict__ wsb,
                            const float* __restrict__ bias,
                            float* __restrict__ out,
                            int ntiles)
{
    __shared__ float tl[2][16][TSTRIDE];   // 16896 B: one 16x128(+pad) tile per wave

    const int tid  = threadIdx.x;
    const int lane = tid & 63;
    const int wave = tid >> 6;
    const int row  = lane & 15;    // x-row within wave tile (D col)
    const int g    = lane >> 4;    // 0..3: k-subgroup on load, out-feature subgroup
    const int gstride = gridDim.x;

    const int rsel = lane >> 5;          // 0/1 for readback/store
    const int c4   = (lane & 31) * 4;    // col start for readback/store

    // bias for this lane's 32 features: [of*16 + g*4 .. +4)
    f32x4 bias_v[8];
    #pragma unroll
    for (int of = 0; of < 8; ++of)
        bias_v[of] = *(const f32x4*)(bias + of * 16 + g * 4);

    // raw x buffer for the software pipeline
    float4 raw[4][2];

    // ---- prologue: issue loads for first tile ----
    {
        long rb = (long)blockIdx.x * 32 + wave * 16;
        const float* rp = x + (rb + row) * D128 + g * 8;
        #pragma unroll
        for (int kk = 0; kk < 4; ++kk) {
            const float4* p = (const float4*)(rp + kk * 32);
            raw[kk][0] = p[0];
            raw[kk][1] = p[1];
        }
    }

    for (int t = blockIdx.x; t < ntiles; t += gstride) {
        const long row_base = (long)t * 32 + wave * 16;

        // ---- cvt raw -> bf16 x fragments (MFMA B-operand) ----
        short8 xfrag[4];
        #pragma unroll
        for (int kk = 0; kk < 4; ++kk) {
            float4 v0 = raw[kk][0];
            float4 v1 = raw[kk][1];
            short8 a;
            a[0] = (short)f2bf(v0.x); a[1] = (short)f2bf(v0.y);
            a[2] = (short)f2bf(v0.z); a[3] = (short)f2bf(v0.w);
            a[4] = (short)f2bf(v1.x); a[5] = (short)f2bf(v1.y);
            a[6] = (short)f2bf(v1.z); a[7] = (short)f2bf(v1.w);
            xfrag[kk] = a;
        }

        // ---- issue next tile's loads (hidden under MFMA + epilogue) ----
        int tn = t + gstride;
        if (tn < ntiles) {
            long rb = (long)tn * 32 + wave * 16;
            const float* rp = x + (rb + row) * D128 + g * 8;
            #pragma unroll
            for (int kk = 0; kk < 4; ++kk) {
                const float4* p = (const float4*)(rp + kk * 32);
                raw[kk][0] = p[0];
                raw[kk][1] = p[1];
            }
        }

        // ---- MFMA: acc[of] = outs [of*16 + g*4 + r] of x-row `row` ----
        f32x4 acc[8];
        #pragma unroll
        for (int of = 0; of < 8; ++of) acc[of] = (f32x4){0.f, 0.f, 0.f, 0.f};

        #pragma unroll
        for (int kk = 0; kk < 4; ++kk) {
            short8 wfrag[8];
            #pragma unroll
            for (int of = 0; of < 8; ++of)
                wfrag[of] = *(const short8*)(wsb + (size_t)((of * 4 + kk) * 64 + lane) * 8);
            #pragma unroll
            for (int of = 0; of < 8; ++of)
                acc[of] = __builtin_amdgcn_mfma_f32_16x16x32_bf16(
                    wfrag[of], xfrag[kk], acc[of], 0, 0, 0);
        }

        // ---- single-pass epilogue: bias, 4-shuffle LN, normalize,
        //      LDS reshape (per-wave, no barrier), 8 full-line NT stores ----
        float s = 0.f, q = 0.f;
        #pragma unroll
        for (int of = 0; of < 8; ++of) {
            acc[of] += bias_v[of];
            #pragma unroll
            for (int r = 0; r < 4; ++r) {
                float z = acc[of][r];
                s += z;
                q += z * z;
            }
        }
        s += __shfl_xor(s, 16, 64);
        s += __shfl_xor(s, 32, 64);
        q += __shfl_xor(q, 16, 64);
        q += __shfl_xor(q, 32, 64);

        float mean = s * (1.0f / 128.0f);
        float var  = q * (1.0f / 128.0f) - mean * mean;
        float rs   = rsqrtf(var + 1e-5f);

        // normalize in place and scatter this lane's 8 f32x4 into its row
        #pragma unroll
        for (int of = 0; of < 8; ++of) {
            f32x4 v;
            #pragma unroll
            for (int r = 0; r < 4; ++r) v[r] = (acc[of][r] - mean) * rs;
            *(f32x4*)&tl[wave][row][of * 16 + g * 4] = v;
        }

        // readback row-major (conflict-free: stride 132) + NT store (1KB/instr)
        #pragma unroll
        for (int it = 0; it < 8; ++it) {
            int rr = 2 * it + rsel;
            f32x4 v = *(const f32x4*)&tl[wave][rr][c4];
            __builtin_nontemporal_store(
                v, (f32x4*)(out + (row_base + rr) * D128 + c4));
        }
    }
}

extern "C" void kernel_launch(void* const* d_in, const int* in_sizes, int n_in,
                              void* d_out, int out_size, void* d_ws, size_t ws_size,
                              hipStream_t stream) {
    const float* x    = (const float*)d_in[0];
    const float* w    = (const float*)d_in[1];
    const float* bias = (const float*)d_in[2];
    float* out        = (float*)d_out;

    int nrows  = in_sizes[0] / D128;   // 262144
    int ntiles = nrows / 32;           // 8192
    int grid   = 1024;                 // persistent: 8 tiles/block, all co-resident

    unsigned short* wsb = (unsigned short*)d_ws;
    hipLaunchKernelGGL(convert_w_kernel, dim3(256), dim3(64), 0, stream, w, wsb);
    hipLaunchKernelGGL(fused_linear_ln_kernel, dim3(grid), dim3(128), 0, stream,
                       x, wsb, bias, out, ntiles);
}